// Round 3
// baseline (997.194 us; speedup 1.0000x reference)
//
#include <hip/hip_runtime.h>
#include <cstdint>

// RBF multi-head self-attention, MI355X gfx950.
// B=2, S=2048, E=1024, H=16, D=64. Outputs (fp32): out[2,2048,1024] ++ attn[2,16,2048,2048].
// Pipeline: cvt -> QKV gemm (fp16 MFMA) -> V transpose -> qM/stats -> fused attn -> out gemm -> LN.
// R3: outputs written as FP32 (reference output dtype). R1/R2 wrote packed bf16 into the fp32
// buffer — readback decoded odd elements vs even refs, absmax 7.20 ≈ sqrt(2)*max|N(0,1)| matched.

typedef _Float16 f16;
typedef _Float16 half8 __attribute__((ext_vector_type(8)));
typedef _Float16 half4 __attribute__((ext_vector_type(4)));
typedef float f32x4 __attribute__((ext_vector_type(4)));

#define LOG2E 1.44269504088896340736f

__device__ __forceinline__ void async_copy16(void* lds, const void* gptr) {
  __builtin_amdgcn_global_load_lds((const __attribute__((address_space(1))) void*)gptr,
                                   (__attribute__((address_space(3))) void*)lds, 16, 0, 0);
}

// ---------------------------------------------------------------- K0: fp32 -> fp16
__global__ __launch_bounds__(256) void cvt_f32_f16(const float* __restrict__ src,
                                                   f16* __restrict__ dst, int n) {
  int i = (blockIdx.x * 256 + threadIdx.x) * 4;
  if (i >= n) return;
  f32x4 v = *(const f32x4*)(src + i);
  half4 h = { (f16)v.x, (f16)v.y, (f16)v.z, (f16)v.w };
  *(half4*)(dst + i) = h;
}

// ---------------------------------------------------------------- K1/K5: 128x128x32 fp16 NT GEMM
// C[row,col] = sum_e A[row,e]*W[col,e]  (both K-major).  MODE 0: QKV proj (z=blockIdx.z picks W/bias,
// writes f16 [z][bh][s][d]).  MODE 1: out proj (+bias +residual, fp32 out).
template<int MODE>
__global__ __launch_bounds__(256, 3) void gemm128(
    const f16* __restrict__ A0, const f16* __restrict__ W0,
    const float* __restrict__ bq, const float* __restrict__ bk, const float* __restrict__ bv,
    f16* __restrict__ qkv, const float* __restrict__ xres, float* __restrict__ outpre) {
  __shared__ f16 As[128 * 32];
  __shared__ f16 Bs[128 * 32];
  const int t = threadIdx.x;
  const int l = t & 63, w = t >> 6;
  const int bn = blockIdx.x, bm = blockIdx.y, z = blockIdx.z;
  const f16* A = A0 + (size_t)bm * 128 * 1024;
  const f16* B = W0 + (size_t)z * 1048576 + (size_t)bn * 128 * 1024;
  const int mh = (w & 1) * 64, nh = (w >> 1) * 64;
  f32x4 acc[16];
#pragma unroll
  for (int i = 0; i < 16; i++) acc[i] = (f32x4){0.f, 0.f, 0.f, 0.f};

  for (int k0 = 0; k0 < 1024; k0 += 32) {
#pragma unroll
    for (int c = 0; c < 2; c++) {
      int lin = t + c * 256;
      int row = lin >> 2, kc = lin & 3;
      async_copy16(As + lin * 8, A + (size_t)row * 1024 + k0 + kc * 8);
      async_copy16(Bs + lin * 8, B + (size_t)row * 1024 + k0 + kc * 8);
    }
    __syncthreads();   // drains vmcnt(0): global_load_lds complete
    half8 af[4], bf[4];
#pragma unroll
    for (int i = 0; i < 4; i++)
      af[i] = *(const half8*)(As + (mh + i * 16 + (l & 15)) * 32 + (l >> 4) * 8);
#pragma unroll
    for (int j = 0; j < 4; j++)
      bf[j] = *(const half8*)(Bs + (nh + j * 16 + (l & 15)) * 32 + (l >> 4) * 8);
#pragma unroll
    for (int i = 0; i < 4; i++)
#pragma unroll
      for (int j = 0; j < 4; j++)
        acc[i * 4 + j] = __builtin_amdgcn_mfma_f32_16x16x32_f16(af[i], bf[j], acc[i * 4 + j], 0, 0, 0);
    __syncthreads();
  }

  const float* bias = (MODE == 1) ? bq : (z == 0 ? bq : (z == 1 ? bk : bv));
#pragma unroll
  for (int i = 0; i < 4; i++) {
#pragma unroll
    for (int j = 0; j < 4; j++) {
      int colg = bn * 128 + nh + j * 16 + (l & 15);
      float bcol = bias[colg];
#pragma unroll
      for (int r = 0; r < 4; r++) {
        int rowg = bm * 128 + mh + i * 16 + (l >> 4) * 4 + r;
        float v = acc[i * 4 + j][r] + bcol;
        if (MODE == 0) {
          int b = rowg >> 11, s = rowg & 2047, h = colg >> 6, d = colg & 63;
          qkv[(((size_t)z * 32 + b * 16 + h) * 2048 + s) * 64 + d] = (f16)v;
        } else {
          v += xres[(size_t)rowg * 1024 + colg];
          outpre[(size_t)rowg * 1024 + colg] = v;
        }
      }
    }
  }
}

// ---------------------------------------------------------------- K2: V [bh][s][d] -> Vt [bh][d][s]
__global__ __launch_bounds__(256) void transpose_v(const f16* __restrict__ Vh, f16* __restrict__ Vt) {
  __shared__ f16 tile[64][72];   // +8 pad: spreads banks on strided reads
  const int t = threadIdx.x;
  const int bh = blockIdx.y, s0 = blockIdx.x * 64;
#pragma unroll
  for (int c = 0; c < 2; c++) {
    int idx = t + c * 256;
    int r = idx >> 3, dc = (idx & 7) * 8;
    half8 v = *(const half8*)(Vh + ((size_t)bh * 2048 + s0 + r) * 64 + dc);
#pragma unroll
    for (int u = 0; u < 8; u++) tile[r][dc + u] = v[u];
  }
  __syncthreads();
#pragma unroll
  for (int c = 0; c < 2; c++) {
    int idx = t + c * 256;
    int d = idx >> 3, sc = (idx & 7) * 8;
    half8 o;
#pragma unroll
    for (int u = 0; u < 8; u++) o[u] = tile[sc + u][d];
    *(half8*)(Vt + ((size_t)bh * 64 + d) * 2048 + s0 + sc) = o;
  }
}

// ---------------------------------------------------------------- K3: qm = Q@M (f16), r=-8*qMq, c=-8*kMk
__global__ __launch_bounds__(256) void qm_stats(const f16* __restrict__ Qh, const f16* __restrict__ Kh,
                                                const float* __restrict__ M, f16* __restrict__ qmh,
                                                float* __restrict__ r8, float* __restrict__ c8) {
  const int side = blockIdx.y;
  const f16* src = side ? Kh : Qh;
  const int t = threadIdx.x, l = t & 63, w = t >> 6;
  const size_t R0 = (size_t)blockIdx.x * 16 + w * 4;   // global row in [0,65536)
  float qv[4], acc[4] = {0.f, 0.f, 0.f, 0.f};
#pragma unroll
  for (int i = 0; i < 4; i++) qv[i] = (float)src[(R0 + i) * 64 + l];
#pragma unroll 8
  for (int d = 0; d < 64; d++) {
    float mc = M[d * 64 + l];                      // M[d][e], lane=e, coalesced + L1-resident
#pragma unroll
    for (int i = 0; i < 4; i++) acc[i] += __shfl(qv[i], d, 64) * mc;
  }
  if (!side) {
#pragma unroll
    for (int i = 0; i < 4; i++) qmh[(R0 + i) * 64 + l] = (f16)acc[i];
  }
  float dots[4];
#pragma unroll
  for (int i = 0; i < 4; i++) dots[i] = qv[i] * acc[i];
#pragma unroll
  for (int off = 1; off < 64; off <<= 1)
#pragma unroll
    for (int i = 0; i < 4; i++) dots[i] += __shfl_xor(dots[i], off, 64);
  if (l == 0) {
    float* o = side ? c8 : r8;
#pragma unroll
    for (int i = 0; i < 4; i++) o[R0 + i] = -8.0f * dots[i];
  }
}

// ---------------------------------------------------------------- K4: fused attention
// WG = (bh, 32-row q-tile), 512 thr / 8 waves. Wave w owns k in [w*256, w*256+256) for all 32 rows:
// scores in 128 VGPRs/lane, softmax via shuffle+LDS reductions. Normalized P then flows through a
// 512-column LDS chunk buffer (4 chunks): chunk write -> PV MFMA partial + coalesced fp32 attn store.
// Static LDS: 32*520*2 + 2048*4 + 128 + 1024 + 1024 = 43,648 B (< 64 KB per-WG limit).
#define PC_STRIDE 520              // 512 + 8 f16 pad: 16B-aligned rows, bank-spread

__global__ __launch_bounds__(512, 2) void attn_kernel(
    const f16* __restrict__ qmh, const f16* __restrict__ Kh, const f16* __restrict__ Vt,
    const float* __restrict__ r8g, const float* __restrict__ c8g,
    f16* __restrict__ ctxh, float* __restrict__ attnf) {
  __shared__ f16 P[32 * PC_STRIDE];     // one 512-col chunk of normalized scores
  __shared__ float c8s[2048];
  __shared__ float r8s[32];
  __shared__ float mstats[32 * 8];
  __shared__ float lstats[32 * 8];

  const int t = threadIdx.x;
  const int l = t & 63, w = t >> 6;
  const int g = l >> 4, li = l & 15;
  const int bh = blockIdx.y;
  const int q0 = blockIdx.x * 32;
  const int b = bh >> 4, h = bh & 15;

  // phase 0: stage column bias (-8*kMk) and row bias (-8*qMq)
  {
    f32x4 cv = *(const f32x4*)(c8g + (size_t)bh * 2048 + t * 4);
    *(f32x4*)(c8s + t * 4) = cv;
    if (t < 32) r8s[t] = r8g[(size_t)bh * 2048 + q0 + t];
  }

  // phase 1: G[q,k] = qm[q,:] . K[k,:]  (K=64 -> 2 MFMA per 16x16 tile)
  half8 af[2][2];
#pragma unroll
  for (int qs = 0; qs < 2; qs++)
#pragma unroll
    for (int kh2 = 0; kh2 < 2; kh2++)
      af[qs][kh2] = *(const half8*)(qmh + ((size_t)bh * 2048 + q0 + qs * 16 + li) * 64 + kh2 * 32 + g * 8);

  f32x4 acc[2][16];
#pragma unroll
  for (int qs = 0; qs < 2; qs++)
#pragma unroll
    for (int ks = 0; ks < 16; ks++) acc[qs][ks] = (f32x4){0.f, 0.f, 0.f, 0.f};

#pragma unroll
  for (int ks = 0; ks < 16; ks++) {
    const f16* kp = Kh + ((size_t)bh * 2048 + w * 256 + ks * 16 + li) * 64 + g * 8;
    half8 b0 = *(const half8*)(kp);
    half8 b1 = *(const half8*)(kp + 32);
#pragma unroll
    for (int qs = 0; qs < 2; qs++) {
      acc[qs][ks] = __builtin_amdgcn_mfma_f32_16x16x32_f16(af[qs][0], b0, acc[qs][ks], 0, 0, 0);
      acc[qs][ks] = __builtin_amdgcn_mfma_f32_16x16x32_f16(af[qs][1], b1, acc[qs][ks], 0, 0, 0);
    }
  }
  __syncthreads();   // c8s/r8s ready

  // phase 2: scores s = 16*G + r[q] + c[k]; per-row max
  float rv[2][4], mrow[2][4];
#pragma unroll
  for (int qs = 0; qs < 2; qs++)
#pragma unroll
    for (int j = 0; j < 4; j++) {
      rv[qs][j] = r8s[qs * 16 + g * 4 + j];
      mrow[qs][j] = -3.0e38f;
    }
#pragma unroll
  for (int ks = 0; ks < 16; ks++) {
    float cv = c8s[w * 256 + ks * 16 + li];
#pragma unroll
    for (int qs = 0; qs < 2; qs++)
#pragma unroll
      for (int j = 0; j < 4; j++) {
        float s = 16.0f * acc[qs][ks][j] + rv[qs][j] + cv;
        acc[qs][ks][j] = s;
        mrow[qs][j] = fmaxf(mrow[qs][j], s);
      }
  }
#pragma unroll
  for (int off = 1; off < 16; off <<= 1)
#pragma unroll
    for (int qs = 0; qs < 2; qs++)
#pragma unroll
      for (int j = 0; j < 4; j++) mrow[qs][j] = fmaxf(mrow[qs][j], __shfl_xor(mrow[qs][j], off, 64));
  if (li == 0)
#pragma unroll
    for (int qs = 0; qs < 2; qs++)
#pragma unroll
      for (int j = 0; j < 4; j++) mstats[(qs * 16 + g * 4 + j) * 8 + w] = mrow[qs][j];
  __syncthreads();

  float mfin[2][4];
#pragma unroll
  for (int qs = 0; qs < 2; qs++)
#pragma unroll
    for (int j = 0; j < 4; j++) {
      float mm = -3.0e38f;
#pragma unroll
      for (int ww = 0; ww < 8; ww++) mm = fmaxf(mm, mstats[(qs * 16 + g * 4 + j) * 8 + ww]);
      mfin[qs][j] = mm;
    }

  // phase 3: p = exp(s - m), row sums
  float ssum[2][4];
#pragma unroll
  for (int qs = 0; qs < 2; qs++)
#pragma unroll
    for (int j = 0; j < 4; j++) ssum[qs][j] = 0.f;
#pragma unroll
  for (int ks = 0; ks < 16; ks++)
#pragma unroll
    for (int qs = 0; qs < 2; qs++)
#pragma unroll
      for (int j = 0; j < 4; j++) {
        float p = exp2f((acc[qs][ks][j] - mfin[qs][j]) * LOG2E);
        acc[qs][ks][j] = p;
        ssum[qs][j] += p;
      }
#pragma unroll
  for (int off = 1; off < 16; off <<= 1)
#pragma unroll
    for (int qs = 0; qs < 2; qs++)
#pragma unroll
      for (int j = 0; j < 4; j++) ssum[qs][j] += __shfl_xor(ssum[qs][j], off, 64);
  if (li == 0)
#pragma unroll
    for (int qs = 0; qs < 2; qs++)
#pragma unroll
      for (int j = 0; j < 4; j++) lstats[(qs * 16 + g * 4 + j) * 8 + w] = ssum[qs][j];
  __syncthreads();

  float inv[2][4];
#pragma unroll
  for (int qs = 0; qs < 2; qs++)
#pragma unroll
    for (int j = 0; j < 4; j++) {
      float tot = 0.f;
#pragma unroll
      for (int ww = 0; ww < 8; ww++) tot += lstats[(qs * 16 + g * 4 + j) * 8 + ww];
      inv[qs][j] = 1.0f / tot;
    }

  // phase 4: chunk loop — stage normalized P for 512 cols, PV partial, attn fp32 store
  const int qs2 = w & 1, dsub = w >> 1;
  f32x4 av = {0.f, 0.f, 0.f, 0.f};
  for (int cc = 0; cc < 4; cc++) {
    if ((w >> 1) == cc) {                       // waves 2cc, 2cc+1 own this chunk's cols
      const int wc = (w & 1) * 256;
#pragma unroll
      for (int ks = 0; ks < 16; ks++)
#pragma unroll
        for (int qs = 0; qs < 2; qs++)
#pragma unroll
          for (int j = 0; j < 4; j++)
            P[(qs * 16 + g * 4 + j) * PC_STRIDE + wc + ks * 16 + li] =
                (f16)(acc[qs][ks][j] * inv[qs][j]);
    }
    __syncthreads();                            // chunk ready

    // PV partial: ctx[q][d] += sum_{k in chunk} P[q][k] * Vt[d][k]
#pragma unroll 4
    for (int kt = 0; kt < 16; kt++) {
      half8 a = *(const half8*)(P + (qs2 * 16 + li) * PC_STRIDE + kt * 32 + g * 8);
      half8 bvv = *(const half8*)(Vt + ((size_t)bh * 64 + dsub * 16 + li) * 2048 +
                                  cc * 512 + kt * 32 + g * 8);
      av = __builtin_amdgcn_mfma_f32_16x16x32_f16(a, bvv, av, 0, 0, 0);
    }

    // attn chunk -> d_out (fp32), coalesced 32B/lane stores
    {
      const int row = t >> 4;
      const int cb = (t & 15) * 8;
#pragma unroll
      for (int i = 0; i < 4; i++) {
        int lcol = cb + i * 128;
        half8 v = *(const half8*)(P + row * PC_STRIDE + lcol);
        float* dst = attnf + ((size_t)bh * 2048 + q0 + row) * 2048 + cc * 512 + lcol;
        f32x4 o0 = { (float)v[0], (float)v[1], (float)v[2], (float)v[3] };
        f32x4 o1 = { (float)v[4], (float)v[5], (float)v[6], (float)v[7] };
        *(f32x4*)(dst) = o0;
        *(f32x4*)(dst + 4) = o1;
      }
    }
    __syncthreads();                            // all reads done before next chunk overwrite
  }

  // ctx store (fp16) for out-projection
#pragma unroll
  for (int j = 0; j < 4; j++) {
    int q = q0 + qs2 * 16 + g * 4 + j;
    ctxh[((size_t)b * 2048 + q) * 1024 + h * 64 + dsub * 16 + li] = (f16)av[j];
  }
}

// ---------------------------------------------------------------- K6: LayerNorm -> fp32
__global__ __launch_bounds__(256) void ln_kernel(const float* __restrict__ src,
                                                 const float* __restrict__ gamma,
                                                 const float* __restrict__ beta,
                                                 float* __restrict__ out) {
  const int r = blockIdx.x, t = threadIdx.x;
  const int l = t & 63, w = t >> 6;
  f32x4 v = *(const f32x4*)(src + (size_t)r * 1024 + t * 4);
  float s1 = v.x + v.y + v.z + v.w;
  float s2 = v.x * v.x + v.y * v.y + v.z * v.z + v.w * v.w;
#pragma unroll
  for (int off = 1; off < 64; off <<= 1) {
    s1 += __shfl_xor(s1, off, 64);
    s2 += __shfl_xor(s2, off, 64);
  }
  __shared__ float a1[4], a2[4];
  if (l == 0) { a1[w] = s1; a2[w] = s2; }
  __syncthreads();
  float t1 = a1[0] + a1[1] + a1[2] + a1[3];
  float t2 = a2[0] + a2[1] + a2[2] + a2[3];
  float mu = t1 * (1.0f / 1024.0f);
  float var = t2 * (1.0f / 1024.0f) - mu * mu;
  float sc = rsqrtf(var + 1e-5f);
  f32x4 gv = *(const f32x4*)(gamma + t * 4);
  f32x4 bv = *(const f32x4*)(beta + t * 4);
  f32x4 o = { (v.x - mu) * sc * gv.x + bv.x,
              (v.y - mu) * sc * gv.y + bv.y,
              (v.z - mu) * sc * gv.z + bv.z,
              (v.w - mu) * sc * gv.w + bv.w };
  *(f32x4*)(out + (size_t)r * 1024 + t * 4) = o;
}

// ---------------------------------------------------------------- launch
extern "C" void kernel_launch(void* const* d_in, const int* in_sizes, int n_in,
                              void* d_out, int out_size, void* d_ws, size_t ws_size,
                              hipStream_t stream) {
  (void)in_sizes; (void)n_in; (void)out_size;
  const float* x  = (const float*)d_in[0];
  const float* Wq = (const float*)d_in[1];
  const float* bq = (const float*)d_in[2];
  const float* Wk = (const float*)d_in[3];
  const float* bk = (const float*)d_in[4];
  const float* Wv = (const float*)d_in[5];
  const float* bv = (const float*)d_in[6];
  const float* M  = (const float*)d_in[7];
  const float* Wo = (const float*)d_in[8];
  const float* bo = (const float*)d_in[9];
  const float* gamma = (const float*)d_in[10];
  const float* beta  = (const float*)d_in[11];

  // workspace layout (59.25 MB; outpre overlays Vh+Vt, ctxh overlays xh — both dead by then)
  char* ws = (char*)d_ws;
  if (ws_size < 59244544) return;
  f16* xh   = (f16*)ws;                      // 8 MB   [4096][1024]
  f16* Wh   = (f16*)(ws + 8388608);          // 8 MB   Wq|Wk|Wv|Wo fp16
  f16* Qh   = (f16*)(ws + 16777216);         // 8 MB   [bh][s][d]
  f16* Kh   = (f16*)(ws + 25165824);         // 8 MB
  f16* Vh   = (f16*)(ws + 33554432);         // 8 MB
  f16* Vt   = (f16*)(ws + 41943040);         // 8 MB   [bh][d][s]
  f16* qmh  = (f16*)(ws + 50331648);         // 8 MB   [bh][s][d]
  float* r8 = (float*)(ws + 58720256);       // 256 KB  -8*qMq
  float* c8 = (float*)(ws + 58982400);       // 256 KB  -8*kMk
  f16* ctxh = xh;                            // reuse (xh dead after QKV gemm)
  float* outpre = (float*)(ws + 33554432);   // 16 MB, reuse Vh+Vt (dead after attn)

  float* outf  = (float*)d_out;
  float* attnf = outf + 4194304;

  cvt_f32_f16<<<4096, 256, 0, stream>>>(x,  xh, 4194304);
  cvt_f32_f16<<<1024, 256, 0, stream>>>(Wq, Wh,            1048576);
  cvt_f32_f16<<<1024, 256, 0, stream>>>(Wk, Wh + 1048576,  1048576);
  cvt_f32_f16<<<1024, 256, 0, stream>>>(Wv, Wh + 2097152,  1048576);
  cvt_f32_f16<<<1024, 256, 0, stream>>>(Wo, Wh + 3145728,  1048576);

  gemm128<0><<<dim3(8, 32, 3), 256, 0, stream>>>(xh, Wh, bq, bk, bv, Qh, nullptr, nullptr);
  transpose_v<<<dim3(32, 32), 256, 0, stream>>>(Vh, Vt);
  qm_stats<<<dim3(4096, 2), 256, 0, stream>>>(Qh, Kh, M, qmh, r8, c8);

  attn_kernel<<<dim3(64, 32), 512, 0, stream>>>(qmh, Kh, Vt, r8, c8, ctxh, attnf);

  gemm128<1><<<dim3(8, 32, 1), 256, 0, stream>>>(ctxh, Wh + 3145728, bo, nullptr, nullptr,
                                                 nullptr, x, outpre);
  ln_kernel<<<4096, 256, 0, stream>>>(outpre, gamma, beta, outf);
}